// Round 9
// baseline (470.770 us; speedup 1.0000x reference)
//
#include <hip/hip_runtime.h>

// Problem dims
#define NN 64
#define EE 128
#define GG 4
#define D0 9
#define H1 2000
#define H2 500
#define H3 100
#define FF1 1000
#define FF2 100
#define FF3 50

// Workspace layout (floats)
#define OFF_P1   28032     // 64*2000          relu(pre1)
#define OFF_Q    156032    // 64*12000         Q2f (Q3f overlays)
#define OFF_PART 924032    // 50*64*500        partials (layer3 overlays)
#define OFF_F1   2562432   // 4*1000
#define OFF_PH   2566448   // 25*400           head2 K-slice partials
#define OFF_SYNC 2576448   // barrier counter (int)

#define NB 128   // co-residency needs only 64 of 256 CUs (LDS 48KB -> 3/CU,
                 // launch_bounds(256,2) -> 2/CU guaranteed): 4x slack.

// ---------------------------------------------------------------------------
// software grid barrier (regular launch, capture-safe, HANG-PROOF):
// tid0 release-adds then acquire-spins with a bounded poll count — worst
// case it proceeds early (visible wrong answer), never a dead container.
// __syncthreads before the release drains the block's global writes
// (compiler emits vmcnt(0) before s_barrier); agent-scope atomics emit the
// L2 writeback/invalidate needed for cross-XCD visibility.
// ---------------------------------------------------------------------------
__device__ __forceinline__ void gsync(int* bar, int target, int tid) {
    __syncthreads();
    if (tid == 0) {
        __hip_atomic_fetch_add(bar, 1, __ATOMIC_ACQ_REL,
                               __HIP_MEMORY_SCOPE_AGENT);
        int spins = 0;
        while (__hip_atomic_load(bar, __ATOMIC_ACQUIRE,
                                 __HIP_MEMORY_SCOPE_AGENT) < target) {
            __builtin_amdgcn_s_sleep(8);
            if (++spins > (1 << 20)) break;   // bounded: fail-visible
        }
    }
    __syncthreads();
}

// ---------------------------------------------------------------------------
// async global->LDS 16B copy. LDS dest is wave-uniform base + lane*16;
// global source address is per-lane.
// ---------------------------------------------------------------------------
__device__ __forceinline__ void gl2lds16(const float* g, float* l) {
    __builtin_amdgcn_global_load_lds(
        (const __attribute__((address_space(1))) unsigned int*)g,
        (__attribute__((address_space(3))) unsigned int*)l,
        16, 0, 0);
}

__device__ __forceinline__ float4 ldf4(const float* p) {
    return *(const float4*)p;
}

// counted vmcnt wait (wave-uniform n). "memory" clobber = compiler fence.
__device__ __forceinline__ void waitcnt_vm_n(int n) {
    switch (n) {
    case 0: asm volatile("s_waitcnt vmcnt(0)" ::: "memory"); break;
    case 2: asm volatile("s_waitcnt vmcnt(2)" ::: "memory"); break;
    case 4: asm volatile("s_waitcnt vmcnt(4)" ::: "memory"); break;
    default: asm volatile("s_waitcnt vmcnt(6)" ::: "memory"); break;
    }
}
__device__ __forceinline__ void cfence() { asm volatile("" ::: "memory"); }

// ---------------------------------------------------------------------------
// per-tile A_d build in LDS (4096 floats). d<4: edge_attr scatter;
// d==4: edge count; d==5: identity. Caller syncs after.
// ---------------------------------------------------------------------------
__device__ __forceinline__ void build_Ad(float* Al, int d,
    const int* __restrict__ ei, const float* __restrict__ ea, int tid)
{
    for (int i = tid; i < NN * NN; i += 256) Al[i] = 0.f;
    __syncthreads();
    if (d == 5) {
        if (tid < NN) Al[tid * 64 + tid] = 1.0f;
    } else if (tid < EE) {
        int s = ei[tid], t = ei[EE + tid];
        float v = (d < 4) ? ea[tid * 4 + d] : 1.0f;
        atomicAdd(&Al[t * 64 + s], v);
    }
}

// ---------------------------------------------------------------------------
// q compute core (round-3/8 validated): Qf[v,d*Kd+k] = sum_u A_d[v][u]*Pl[u][k]
// ---------------------------------------------------------------------------
template<int Kd, int KTOT>
__device__ __forceinline__ void q_compute_store(
    const float* Al, const float* Pl, float* __restrict__ Qf,
    int d, int k0, int tid)
{
    const int kq = tid & 31, rg = tid >> 5;
    float acc[8][4] = {};
    #pragma unroll 4
    for (int u4 = 0; u4 < 16; ++u4) {
        float4 pv0 = ldf4(&Pl[(u4 * 4 + 0) * 128 + kq * 4]);
        float4 pv1 = ldf4(&Pl[(u4 * 4 + 1) * 128 + kq * 4]);
        float4 pv2 = ldf4(&Pl[(u4 * 4 + 2) * 128 + kq * 4]);
        float4 pv3 = ldf4(&Pl[(u4 * 4 + 3) * 128 + kq * 4]);
        #pragma unroll
        for (int i = 0; i < 8; ++i) {
            float4 a = ldf4(&Al[(rg * 8 + i) * 64 + u4 * 4]);
            acc[i][0] += a.x * pv0.x + a.y * pv1.x + a.z * pv2.x + a.w * pv3.x;
            acc[i][1] += a.x * pv0.y + a.y * pv1.y + a.z * pv2.y + a.w * pv3.y;
            acc[i][2] += a.x * pv0.z + a.y * pv1.z + a.z * pv2.z + a.w * pv3.z;
            acc[i][3] += a.x * pv0.w + a.y * pv1.w + a.z * pv2.w + a.w * pv3.w;
        }
    }
    const int k = k0 + kq * 4;
    if (k < Kd) {
        #pragma unroll
        for (int i = 0; i < 8; ++i) {
            int r = rg * 8 + i;
            *(float4*)(Qf + r * KTOT + d * Kd + k) =
                make_float4(acc[i][0], acc[i][1], acc[i][2], acc[i][3]);
        }
    }
}

// ---------------------------------------------------------------------------
// split phase (round-3/8 validated counted-vmcnt double buffer), as a
// grid-stride device function. Tile-loop safety: each tile ends with
// vmcnt(0) on its final iteration + trailing s_barrier, so next tile's
// stage(0) cannot race previous tile's LDS reads.
// ---------------------------------------------------------------------------
template<int M, int S, int ITERS, int T1, int T2>
__device__ void split_phase(float* sm, const float* __restrict__ Qf,
    const float* __restrict__ We, const float* __restrict__ be,
    const float* __restrict__ root, float* __restrict__ part,
    int bx, int nb, int tid)
{
    constexpr int KC = 20, BN = 64;
    constexpr int KTOT = S * ITERS * KC;
    constexpr int OT = (M + BN - 1) / BN;
    const int tx = tid & 15, ty = tid >> 4;
    const int wv = tid >> 6, ln = tid & 63;
    float* As = sm;            // 2 x 1280  [row][k]
    float* Bs = sm + 2560;     // 2 x 1280  [k][col]
    const int nw = (wv == 0) ? 4 : 2;   // per-wave VMEM issues per stage()

    for (int t = bx; t < OT * S; t += nb) {
        const int s = t % S, ot = t / S;
        const int o0 = ot * BN;
        const int kbase = s * (KC * ITERS);

        auto stage = [&](int bf, int kb) {
            for (int c = wv; c < 5; c += 4) {        // A: 1280 fl = 5 chunks
                int f = c * 256 + ln * 4;
                int r = f / KC, kkk = f - r * KC;
                gl2lds16(Qf + r * KTOT + kb + kkk, As + bf * 1280 + c * 256);
            }
            for (int c = wv; c < 5; c += 4) {        // B: 1280 fl = 5 chunks
                int f = c * 256 + ln * 4;
                int krow = f >> 6, col = f & 63;
                int kg = kb + krow;
                const float* bp = (kg < T1) ? (We + (long long)kg * M)
                                : (kg < T2) ? (be + (long long)(kg - T1) * M)
                                            : (root + (long long)(kg - T2) * M);
                int cc = min(o0 + col, M - 4);       // clamp keeps 16B align
                gl2lds16(bp + cc, Bs + bf * 1280 + c * 256);
            }
        };

        float acc[4][4] = {};
        stage(0, kbase);
        for (int it = 0; it < ITERS; ++it) {
            int npend = 0;
            if (it + 1 < ITERS) { stage((it + 1) & 1, kbase + (it + 1) * KC); npend = nw; }
            waitcnt_vm_n(npend);                 // own current-buf loads done
            __builtin_amdgcn_s_barrier();        // all waves' writes visible
            __builtin_amdgcn_sched_barrier(0);

            const float* Ab = As + (it & 1) * 1280;
            const float* Bb = Bs + (it & 1) * 1280;
            #pragma unroll
            for (int k4 = 0; k4 < 5; ++k4) {
                float4 av[4], bv[4];
                #pragma unroll
                for (int i = 0; i < 4; ++i)
                    av[i] = ldf4(&Ab[(ty * 4 + i) * KC + k4 * 4]);
                #pragma unroll
                for (int q = 0; q < 4; ++q)
                    bv[q] = ldf4(&Bb[(k4 * 4 + q) * BN + tx * 4]);
                #pragma unroll
                for (int i = 0; i < 4; ++i) {
                    acc[i][0] += av[i].x * bv[0].x; acc[i][1] += av[i].x * bv[0].y;
                    acc[i][2] += av[i].x * bv[0].z; acc[i][3] += av[i].x * bv[0].w;
                    acc[i][0] += av[i].y * bv[1].x; acc[i][1] += av[i].y * bv[1].y;
                    acc[i][2] += av[i].y * bv[1].z; acc[i][3] += av[i].y * bv[1].w;
                    acc[i][0] += av[i].z * bv[2].x; acc[i][1] += av[i].z * bv[2].y;
                    acc[i][2] += av[i].z * bv[2].z; acc[i][3] += av[i].z * bv[2].w;
                    acc[i][0] += av[i].w * bv[3].x; acc[i][1] += av[i].w * bv[3].y;
                    acc[i][2] += av[i].w * bv[3].z; acc[i][3] += av[i].w * bv[3].w;
                }
            }
            cfence();
            __builtin_amdgcn_sched_barrier(0);
            __builtin_amdgcn_s_barrier();        // reads done before overwrite
        }

        float* dst = part + s * (64 * M);
        #pragma unroll
        for (int i = 0; i < 4; ++i) {
            int u = ty * 4 + i;
            #pragma unroll
            for (int jj = 0; jj < 4; ++jj) {
                int j = o0 + tx * 4 + jj;
                if (j < M) dst[u * M + j] = acc[i][jj];
            }
        }
    }
}

// ---------------------------------------------------------------------------
// barrier-counter zero (stream-ordered before k_fused; capture-safe)
// ---------------------------------------------------------------------------
__global__ void k_bz(float* ws) {
    if (threadIdx.x == 0) *(int*)(ws + OFF_SYNC) = 0;
}

// ---------------------------------------------------------------------------
// The whole network in one kernel; 8 phases, 7 software grid syncs.
// Phase bodies = round-8 verified kernels (absmax 0.0) as tile loops.
// ---------------------------------------------------------------------------
__global__ __launch_bounds__(256, 2) void k_fused(
    const float* __restrict__ x, const int* __restrict__ edge_index,
    const float* __restrict__ edge_attr, const int* __restrict__ batch,
    const float* __restrict__ We1, const float* __restrict__ be1,
    const float* __restrict__ root1, const float* __restrict__ b1,
    const float* __restrict__ We2, const float* __restrict__ be2,
    const float* __restrict__ root2, const float* __restrict__ b2,
    const float* __restrict__ We3, const float* __restrict__ be3,
    const float* __restrict__ root3, const float* __restrict__ b3,
    const float* __restrict__ W1, const float* __restrict__ c1,
    const float* __restrict__ W2, const float* __restrict__ c2,
    const float* __restrict__ W3, const float* __restrict__ c3,
    const float* __restrict__ W4, const float* __restrict__ c4,
    float* __restrict__ ws, float* __restrict__ out)
{
    __shared__ __align__(16) float sm[12288];    // 48 KB union
    const int bx = blockIdx.x, nb = gridDim.x, tid = threadIdx.x;
    int* bar = (int*)(ws + OFF_SYNC);
    int bt = 0;

    // ---- phase 1: P1 = relu(b1 + Y @ Wall1), Y built once in LDS ---------
    {
        float* Ys = sm;            // 64*56
        float* Bs = sm + 3584;     // 54*64
        const int tx = tid & 15, ty = tid >> 4;
        float* P1 = ws + OFF_P1;
        for (int i = tid; i < 64 * 56; i += 256) Ys[i] = 0.f;
        __syncthreads();
        if (tid < EE) {
            int s = edge_index[tid], t = edge_index[EE + tid];
            float ea[4];
            #pragma unroll
            for (int d = 0; d < 4; ++d) ea[d] = edge_attr[tid * 4 + d];
            #pragma unroll
            for (int i = 0; i < D0; ++i) {
                float xv = x[s * D0 + i];
                #pragma unroll
                for (int d = 0; d < 4; ++d)
                    atomicAdd(&Ys[t * 56 + d * 9 + i], ea[d] * xv);
                atomicAdd(&Ys[t * 56 + 36 + i], xv);
            }
        }
        if (tid < NN) {
            #pragma unroll
            for (int i = 0; i < D0; ++i) Ys[tid * 56 + 45 + i] = x[tid * D0 + i];
        }
        for (int t = bx; t < 32; t += nb) {
            const int o0 = t * 64;
            const int w = min(64, H1 - o0);      // 2048 > 2000 guard
            __syncthreads();                     // Ys ready / Bs reuse safe
            for (int i = tid; i < 54 * 64; i += 256) {
                int r = i >> 6, c = i & 63;
                int d = r / 9, ii = r - d * 9;
                const float* rowp = ((d < 4) ? (We1 + d * (D0 * H1))
                                             : ((d == 4) ? be1 : root1)) + ii * H1;
                Bs[r * 64 + c] = (c < w) ? rowp[o0 + c] : 0.f;
            }
            __syncthreads();
            float acc[4][4] = {};
            #pragma unroll 6
            for (int r = 0; r < 54; ++r) {
                float a0 = Ys[(ty * 4 + 0) * 56 + r];
                float a1 = Ys[(ty * 4 + 1) * 56 + r];
                float a2 = Ys[(ty * 4 + 2) * 56 + r];
                float a3 = Ys[(ty * 4 + 3) * 56 + r];
                const float4 bv = *(const float4*)&Bs[r * 64 + tx * 4];
                acc[0][0] += a0 * bv.x; acc[0][1] += a0 * bv.y; acc[0][2] += a0 * bv.z; acc[0][3] += a0 * bv.w;
                acc[1][0] += a1 * bv.x; acc[1][1] += a1 * bv.y; acc[1][2] += a1 * bv.z; acc[1][3] += a1 * bv.w;
                acc[2][0] += a2 * bv.x; acc[2][1] += a2 * bv.y; acc[2][2] += a2 * bv.z; acc[2][3] += a2 * bv.w;
                acc[3][0] += a3 * bv.x; acc[3][1] += a3 * bv.y; acc[3][2] += a3 * bv.z; acc[3][3] += a3 * bv.w;
            }
            #pragma unroll
            for (int i = 0; i < 4; ++i) {
                int u = ty * 4 + i;
                #pragma unroll
                for (int jj = 0; jj < 4; ++jj) {
                    int j = o0 + tx * 4 + jj;
                    if (j < H1) {
                        float v = b1[j] + acc[i][jj];
                        P1[u * H1 + j] = v > 0.f ? v : 0.f;
                    }
                }
            }
        }
    }
    bt += NB; gsync(bar, bt, tid);

    // ---- phase 2: Q2f = A_d @ P1  (96 tiles; A_d built per tile) ---------
    {
        float* Al = sm;          // 4096
        float* Pl = sm + 4096;   // 8192
        const float* P1 = ws + OFF_P1;
        float* Qf = ws + OFF_Q;
        for (int t = bx; t < 96; t += nb) {
            const int d = t / 16, kt = t % 16;
            const int k0 = kt * 128;
            const int nf4 = (min(128, 2000 - k0) + 3) >> 2;
            __syncthreads();                 // prev tile LDS reads done
            build_Ad(Al, d, edge_index, edge_attr, tid);
            for (int i4 = tid; i4 < 2048; i4 += 256) {
                int u = i4 >> 5, c4 = i4 & 31;
                float4 v = {0.f, 0.f, 0.f, 0.f};
                if (c4 < nf4) v = ldf4(P1 + u * 2000 + k0 + c4 * 4);
                *(float4*)&Pl[u * 128 + c4 * 4] = v;
            }
            __syncthreads();
            q_compute_store<2000, 12000>(Al, Pl, Qf, d, k0, tid);
        }
    }
    bt += NB; gsync(bar, bt, tid);

    // ---- phase 3: part2 = Q2f @ Wstack2  (400 tiles) ---------------------
    split_phase<500, 50, 12, 8000, 10000>(sm, ws + OFF_Q, We2, be2, root2,
                                          ws + OFF_PART, bx, nb, tid);
    bt += NB; gsync(bar, bt, tid);

    // ---- phase 4: Q3f = A_d @ relu(b2 + sum part2)  (24 tiles, fold) -----
    {
        float* Al = sm;
        float* Pl = sm + 4096;
        const float* part = ws + OFF_PART;
        float* Qf = ws + OFF_Q;
        for (int t = bx; t < 24; t += nb) {
            const int d = t / 4, kt = t % 4;
            const int k0 = kt * 128;
            __syncthreads();
            build_Ad(Al, d, edge_index, edge_attr, tid);
            for (int i4 = tid; i4 < 2048; i4 += 256) {
                int u = i4 >> 5, c4 = i4 & 31;
                int k = k0 + c4 * 4;                 // 500%4==0 -> safe
                float4 acc = {0.f, 0.f, 0.f, 0.f};
                if (k < 500) {
                    acc = ldf4(b2 + k);
                    #pragma unroll 10
                    for (int s = 0; s < 50; ++s) {
                        float4 v = ldf4(part + s * (NN * 500) + u * 500 + k);
                        acc.x += v.x; acc.y += v.y; acc.z += v.z; acc.w += v.w;
                    }
                    acc.x = fmaxf(acc.x, 0.f); acc.y = fmaxf(acc.y, 0.f);
                    acc.z = fmaxf(acc.z, 0.f); acc.w = fmaxf(acc.w, 0.f);
                }
                *(float4*)&Pl[u * 128 + c4 * 4] = acc;
            }
            __syncthreads();
            q_compute_store<500, 3000>(Al, Pl, Qf, d, k0, tid);
        }
    }
    bt += NB; gsync(bar, bt, tid);

    // ---- phase 5: part3 = Q3f @ Wstack3  (100 tiles) ---------------------
    split_phase<100, 50, 3, 2000, 2500>(sm, ws + OFF_Q, We3, be3, root3,
                                        ws + OFF_PART, bx, nb, tid);
    bt += NB; gsync(bar, bt, tid);

    // ---- phase 6: fold red3 + segsum + f1 = relu(c1 + g@W1)  (64 tiles) --
    {
        float* pre3s = sm;                    // 6400
        int*   bsh   = (int*)(sm + 6400);     // 64
        float* gs    = sm + 6464;             // 100
        float* red   = sm + 6576;             // 256
        const float* part = ws + OFF_PART;
        float* f1 = ws + OFF_F1;
        for (int i4 = tid; i4 < 1600; i4 += 256) {
            int off = i4 * 4;
            float4 acc = ldf4(b3 + off % H3);
            #pragma unroll 10
            for (int s = 0; s < 50; ++s) {
                float4 v = ldf4(part + s * (NN * H3) + off);
                acc.x += v.x; acc.y += v.y; acc.z += v.z; acc.w += v.w;
            }
            *(float4*)&pre3s[off] = acc;
        }
        if (tid < NN) bsh[tid] = batch[tid];
        __syncthreads();
        for (int t = bx; t < 64; t += nb) {
            const int gi = t >> 4, jt = t & 15, o0 = jt * 64;
            for (int d = tid; d < H3; d += 256) {
                float acc = 0.f;
                #pragma unroll
                for (int v = 0; v < NN; ++v) {
                    float h = pre3s[v * H3 + d];
                    h = h > 0.f ? h : 0.f;
                    acc += (bsh[v] == gi) ? h : 0.f;
                }
                gs[d] = acc;
            }
            __syncthreads();
            const int jj = tid & 63, kq = tid >> 6;
            const int oc = min(o0 + jj, FF1 - 1);
            float p = 0.f;
            #pragma unroll
            for (int k = kq * 25; k < kq * 25 + 25; ++k)
                p += gs[k] * W1[k * FF1 + oc];
            red[kq * 64 + jj] = p;
            __syncthreads();
            if (tid < 64) {
                int o = o0 + tid;
                if (o < FF1) {
                    float v = c1[o] + red[tid] + red[64 + tid] + red[128 + tid] + red[192 + tid];
                    f1[gi * FF1 + o] = v > 0.f ? v : 0.f;
                }
            }
            __syncthreads();      // gs/red reuse next tile
        }
    }
    bt += NB; gsync(bar, bt, tid);

    // ---- phase 7: ph[s] = f1 @ W2 K-slice partials  (25 tiles) -----------
    {
        float* f1s = sm;
        const float* f1 = ws + OFF_F1;
        float* ph = ws + OFF_PH;
        for (int t = bx; t < 25; t += nb) {
            const int k0 = t * 40;
            __syncthreads();
            for (int i = tid; i < GG * 40; i += 256) {
                int gi = i / 40, kk = i - gi * 40;
                f1s[i] = f1[gi * FF1 + k0 + kk];
            }
            __syncthreads();
            for (int idx = tid; idx < GG * FF2; idx += 256) {
                int gi = idx / FF2, o = idx - gi * FF2;
                float acc = 0.f;
                #pragma unroll 8
                for (int kk = 0; kk < 40; ++kk)
                    acc += f1s[gi * 40 + kk] * W2[(k0 + kk) * FF2 + o];
                ph[t * (GG * FF2) + idx] = acc;
            }
        }
    }
    bt += NB; gsync(bar, bt, tid);

    // ---- phase 8: f2 = relu(c2 + sum ph); f3; out  (block 0) -------------
    if (bx == 0) {
        float* f2s = sm;            // GG*FF2
        float* f3s = sm + 512;      // GG*FF3
        const float* ph = ws + OFF_PH;
        for (int idx = tid; idx < GG * FF2; idx += 256) {
            int o = idx % FF2;
            float acc = c2[o];
            #pragma unroll 5
            for (int s = 0; s < 25; ++s) acc += ph[s * (GG * FF2) + idx];
            f2s[idx] = acc > 0.f ? acc : 0.f;
        }
        __syncthreads();
        if (tid < GG * FF3) {
            int gi = tid / FF3, o = tid - gi * FF3;
            float acc = c3[o];
            #pragma unroll 4
            for (int k = 0; k < FF2; ++k)
                acc += f2s[gi * FF2 + k] * W3[k * FF3 + o];
            f3s[tid] = acc > 0.f ? acc : 0.f;
        }
        __syncthreads();
        if (tid < GG) {
            float acc = c4[0];
            #pragma unroll
            for (int k = 0; k < FF3; ++k) acc += f3s[tid * FF3 + k] * W4[k];
            out[tid] = acc;
        }
    }
}

extern "C" void kernel_launch(void* const* d_in, const int* in_sizes, int n_in,
                              void* d_out, int out_size, void* d_ws, size_t ws_size,
                              hipStream_t stream) {
    const float* x          = (const float*)d_in[0];
    const int*   edge_index = (const int*)  d_in[1];
    const float* edge_attr  = (const float*)d_in[2];
    const int*   batch      = (const int*)  d_in[3];
    const float* We1 = (const float*)d_in[4];
    const float* be1 = (const float*)d_in[5];
    const float* root1 = (const float*)d_in[6];
    const float* b1  = (const float*)d_in[7];
    const float* We2 = (const float*)d_in[8];
    const float* be2 = (const float*)d_in[9];
    const float* root2 = (const float*)d_in[10];
    const float* b2  = (const float*)d_in[11];
    const float* We3 = (const float*)d_in[12];
    const float* be3 = (const float*)d_in[13];
    const float* root3 = (const float*)d_in[14];
    const float* b3  = (const float*)d_in[15];
    const float* W1 = (const float*)d_in[16];
    const float* c1 = (const float*)d_in[17];
    const float* W2 = (const float*)d_in[18];
    const float* c2 = (const float*)d_in[19];
    const float* W3 = (const float*)d_in[20];
    const float* c3 = (const float*)d_in[21];
    const float* W4 = (const float*)d_in[22];
    const float* c4 = (const float*)d_in[23];
    float* ws  = (float*)d_ws;
    float* out = (float*)d_out;

    k_bz<<<1, 64, 0, stream>>>(ws);
    k_fused<<<NB, 256, 0, stream>>>(
        x, edge_index, edge_attr, batch,
        We1, be1, root1, b1,
        We2, be2, root2, b2,
        We3, be3, root3, b3,
        W1, c1, W2, c2, W3, c3, W4, c4,
        ws, out);
}

// Round 10
// 212.978 us; speedup vs baseline: 2.2104x; 2.2104x over previous
//
#include <hip/hip_runtime.h>

// Problem dims
#define NN 64
#define EE 128
#define GG 4
#define D0 9
#define H1 2000
#define H2 500
#define H3 100
#define FF1 1000
#define FF2 100
#define FF3 50

// Workspace layout (floats)
#define OFF_P1   28032     // 64*2000          relu(pre1)
#define OFF_Q    156032    // 64*12000         Q2f (Q3f overlays)
#define OFF_PART 924032    // 50*64*500        partials (layer3 overlays)
#define OFF_P2   2524032   // 64*500           relu(pre2)
#define OFF_PRE3 2556032   // 64*100           pre3 (raw)
#define OFF_F1   2562432   // 4*1000
#define OFF_PH   2566448   // 25*400           head2 K-slice partials

// ---------------------------------------------------------------------------
// async global->LDS 16B copy. LDS dest is wave-uniform base + lane*16;
// global source address is per-lane.
// ---------------------------------------------------------------------------
__device__ __forceinline__ void gl2lds16(const float* g, float* l) {
    __builtin_amdgcn_global_load_lds(
        (const __attribute__((address_space(1))) unsigned int*)g,
        (__attribute__((address_space(3))) unsigned int*)l,
        16, 0, 0);
}

__device__ __forceinline__ float4 ldf4(const float* p) {
    return *(const float4*)p;
}

// counted vmcnt wait (wave-uniform n). "memory" clobber = compiler fence.
__device__ __forceinline__ void waitcnt_vm_n(int n) {
    switch (n) {
    case 0: asm volatile("s_waitcnt vmcnt(0)" ::: "memory"); break;
    case 2: asm volatile("s_waitcnt vmcnt(2)" ::: "memory"); break;
    case 4: asm volatile("s_waitcnt vmcnt(4)" ::: "memory"); break;
    default: asm volatile("s_waitcnt vmcnt(6)" ::: "memory"); break;
    }
}
__device__ __forceinline__ void cfence() { asm volatile("" ::: "memory"); }

// ---------------------------------------------------------------------------
// per-block A_d build in LDS (4096 floats). d<4: edge_attr scatter;
// d==4: edge count; d==5: identity. LDS atomics only. Caller syncs after.
// ---------------------------------------------------------------------------
__device__ __forceinline__ void build_Ad(float* Al, int d,
    const int* __restrict__ ei, const float* __restrict__ ea, int tid)
{
    for (int i = tid; i < NN * NN; i += 256) Al[i] = 0.f;
    __syncthreads();
    if (d == 5) {
        if (tid < NN) Al[tid * 64 + tid] = 1.0f;
    } else if (tid < EE) {
        int s = ei[tid], t = ei[EE + tid];
        float v = (d < 4) ? ea[tid * 4 + d] : 1.0f;
        atomicAdd(&Al[t * 64 + s], v);
    }
}

// ---------------------------------------------------------------------------
// q compute core (validated rounds 3/8): Qf[v,d*Kd+k] = sum_u A_d[v][u]*Pl[u][k]
// thread = (col-quad kq 0..31, row-group rg 0..7 of 8 rows).
// ---------------------------------------------------------------------------
template<int Kd, int KTOT>
__device__ __forceinline__ void q_compute_store(
    const float* Al, const float* Pl, float* __restrict__ Qf,
    int d, int k0, int tid)
{
    const int kq = tid & 31, rg = tid >> 5;
    float acc[8][4] = {};
    #pragma unroll 4
    for (int u4 = 0; u4 < 16; ++u4) {
        float4 pv0 = ldf4(&Pl[(u4 * 4 + 0) * 128 + kq * 4]);
        float4 pv1 = ldf4(&Pl[(u4 * 4 + 1) * 128 + kq * 4]);
        float4 pv2 = ldf4(&Pl[(u4 * 4 + 2) * 128 + kq * 4]);
        float4 pv3 = ldf4(&Pl[(u4 * 4 + 3) * 128 + kq * 4]);
        #pragma unroll
        for (int i = 0; i < 8; ++i) {
            float4 a = ldf4(&Al[(rg * 8 + i) * 64 + u4 * 4]);
            acc[i][0] += a.x * pv0.x + a.y * pv1.x + a.z * pv2.x + a.w * pv3.x;
            acc[i][1] += a.x * pv0.y + a.y * pv1.y + a.z * pv2.y + a.w * pv3.y;
            acc[i][2] += a.x * pv0.z + a.y * pv1.z + a.z * pv2.z + a.w * pv3.z;
            acc[i][3] += a.x * pv0.w + a.y * pv1.w + a.z * pv2.w + a.w * pv3.w;
        }
    }
    const int k = k0 + kq * 4;
    if (k < Kd) {
        #pragma unroll
        for (int i = 0; i < 8; ++i) {
            int r = rg * 8 + i;
            *(float4*)(Qf + r * KTOT + d * Kd + k) =
                make_float4(acc[i][0], acc[i][1], acc[i][2], acc[i][3]);
        }
    }
}

// ---------------------------------------------------------------------------
// K1: P1 = relu(b1 + Y @ Wall1). Y built per-block in LDS (verified r7/r8).
// ---------------------------------------------------------------------------
__global__ __launch_bounds__(256) void k_p1(
    const float* __restrict__ x, const int* __restrict__ edge_index,
    const float* __restrict__ edge_attr,
    const float* __restrict__ We1, const float* __restrict__ be1,
    const float* __restrict__ root1, const float* __restrict__ b1,
    float* __restrict__ P1)
{
    __shared__ float Ys[64 * 56];
    __shared__ __align__(16) float Bs[54 * 64];
    const int tid = threadIdx.x;
    const int tx = tid & 15, ty = tid >> 4;
    const int o0 = blockIdx.x * 64;
    const int w = min(64, H1 - o0);      // 32*64=2048 > 2000

    for (int i = tid; i < 64 * 56; i += 256) Ys[i] = 0.f;
    __syncthreads();
    if (tid < EE) {
        int s = edge_index[tid], t = edge_index[EE + tid];
        float ea[4];
        #pragma unroll
        for (int d = 0; d < 4; ++d) ea[d] = edge_attr[tid * 4 + d];
        #pragma unroll
        for (int i = 0; i < D0; ++i) {
            float xv = x[s * D0 + i];
            #pragma unroll
            for (int d = 0; d < 4; ++d)
                atomicAdd(&Ys[t * 56 + d * 9 + i], ea[d] * xv);
            atomicAdd(&Ys[t * 56 + 36 + i], xv);
        }
    }
    if (tid < NN) {
        #pragma unroll
        for (int i = 0; i < D0; ++i) Ys[tid * 56 + 45 + i] = x[tid * D0 + i];
    }
    for (int i = tid; i < 54 * 64; i += 256) {
        int r = i >> 6, c = i & 63;
        int d = r / 9, ii = r - d * 9;
        const float* rowp = ((d < 4) ? (We1 + d * (D0 * H1))
                                     : ((d == 4) ? be1 : root1)) + ii * H1;
        Bs[r * 64 + c] = (c < w) ? rowp[o0 + c] : 0.f;
    }
    __syncthreads();

    float acc[4][4] = {};
    #pragma unroll 6
    for (int r = 0; r < 54; ++r) {
        float a0 = Ys[(ty * 4 + 0) * 56 + r];
        float a1 = Ys[(ty * 4 + 1) * 56 + r];
        float a2 = Ys[(ty * 4 + 2) * 56 + r];
        float a3 = Ys[(ty * 4 + 3) * 56 + r];
        const float4 bv = *(const float4*)&Bs[r * 64 + tx * 4];
        acc[0][0] += a0 * bv.x; acc[0][1] += a0 * bv.y; acc[0][2] += a0 * bv.z; acc[0][3] += a0 * bv.w;
        acc[1][0] += a1 * bv.x; acc[1][1] += a1 * bv.y; acc[1][2] += a1 * bv.z; acc[1][3] += a1 * bv.w;
        acc[2][0] += a2 * bv.x; acc[2][1] += a2 * bv.y; acc[2][2] += a2 * bv.z; acc[2][3] += a2 * bv.w;
        acc[3][0] += a3 * bv.x; acc[3][1] += a3 * bv.y; acc[3][2] += a3 * bv.z; acc[3][3] += a3 * bv.w;
    }
    #pragma unroll
    for (int i = 0; i < 4; ++i) {
        int u = ty * 4 + i;
        #pragma unroll
        for (int jj = 0; jj < 4; ++jj) {
            int j = o0 + tx * 4 + jj;
            if (j < H1) {
                float v = b1[j] + acc[i][jj];
                P1[u * H1 + j] = v > 0.f ? v : 0.f;
            }
        }
    }
}

// ---------------------------------------------------------------------------
// k_qp: Qf = A_d @ P, P read directly from global (verified r8).
// ---------------------------------------------------------------------------
template<int Kd, int KTOT, int NKT>
__global__ __launch_bounds__(256) void k_qp(
    const int* __restrict__ edge_index, const float* __restrict__ edge_attr,
    const float* __restrict__ P, float* __restrict__ Qf)
{
    __shared__ __align__(16) float Al[64 * 64];
    __shared__ __align__(16) float Pl[64 * 128];
    const int tid = threadIdx.x;
    const int d = blockIdx.x / NKT, kt = blockIdx.x % NKT;
    const int k0 = kt * 128;
    const int nf4 = (min(128, Kd - k0) + 3) >> 2;

    build_Ad(Al, d, edge_index, edge_attr, tid);
    for (int i4 = tid; i4 < 2048; i4 += 256) {
        int u = i4 >> 5, c4 = i4 & 31;
        float4 v = {0.f, 0.f, 0.f, 0.f};
        if (c4 < nf4) v = ldf4(P + u * Kd + k0 + c4 * 4);
        *(float4*)&Pl[u * 128 + c4 * 4] = v;
    }
    __syncthreads();
    q_compute_store<Kd, KTOT>(Al, Pl, Qf, d, k0, tid);
}

// ---------------------------------------------------------------------------
// k_split: part[s][64][M] = Qf[64 x span] @ Wstk (col stripe o0..o0+63).
//   Counted-vmcnt double buffer (verified r3/r8). Non-atomic slice output.
// ---------------------------------------------------------------------------
template<int M, int S, int ITERS, int T1, int T2>
__global__ __launch_bounds__(256) void k_split(
    const float* __restrict__ Qf, const float* __restrict__ We,
    const float* __restrict__ be, const float* __restrict__ root,
    float* __restrict__ part)
{
    constexpr int KC = 20, BN = 64;
    constexpr int KTOT = S * ITERS * KC;
    const int b = blockIdx.x;
    const int s = b % S, ot = b / S;
    const int o0 = ot * BN;
    const int tid = threadIdx.x;
    const int tx = tid & 15, ty = tid >> 4;
    const int wv = tid >> 6, ln = tid & 63;
    const int kbase = s * (KC * ITERS);
    const int nw = (wv == 0) ? 4 : 2;   // per-wave VMEM issues per stage()

    __shared__ __align__(16) float As[2][64 * KC];   // [row][k]
    __shared__ __align__(16) float Bs[2][KC * BN];   // [k][col]

    auto stage = [&](int bf, int kb) {
        for (int c = wv; c < 5; c += 4) {            // A: 1280 fl = 5 chunks
            int f = c * 256 + ln * 4;
            int r = f / KC, kkk = f - r * KC;
            gl2lds16(Qf + r * KTOT + kb + kkk, &As[bf][c * 256]);
        }
        for (int c = wv; c < 5; c += 4) {            // B: 1280 fl = 5 chunks
            int f = c * 256 + ln * 4;
            int krow = f >> 6, col = f & 63;
            int kg = kb + krow;
            const float* bp = (kg < T1) ? (We + (long long)kg * M)
                            : (kg < T2) ? (be + (long long)(kg - T1) * M)
                                        : (root + (long long)(kg - T2) * M);
            int cc = min(o0 + col, M - 4);           // clamp keeps 16B align
            gl2lds16(bp + cc, &Bs[bf][c * 256]);
        }
    };

    float acc[4][4] = {};
    stage(0, kbase);
    for (int it = 0; it < ITERS; ++it) {
        int npend = 0;
        if (it + 1 < ITERS) { stage((it + 1) & 1, kbase + (it + 1) * KC); npend = nw; }
        waitcnt_vm_n(npend);                 // own current-buf loads done
        __builtin_amdgcn_s_barrier();        // all waves' writes visible
        __builtin_amdgcn_sched_barrier(0);

        const float* Ab = As[it & 1];
        const float* Bb = Bs[it & 1];
        #pragma unroll
        for (int k4 = 0; k4 < 5; ++k4) {
            float4 av[4], bv[4];
            #pragma unroll
            for (int i = 0; i < 4; ++i)
                av[i] = ldf4(&Ab[(ty * 4 + i) * KC + k4 * 4]);
            #pragma unroll
            for (int q = 0; q < 4; ++q)
                bv[q] = ldf4(&Bb[(k4 * 4 + q) * BN + tx * 4]);
            #pragma unroll
            for (int i = 0; i < 4; ++i) {
                acc[i][0] += av[i].x * bv[0].x; acc[i][1] += av[i].x * bv[0].y;
                acc[i][2] += av[i].x * bv[0].z; acc[i][3] += av[i].x * bv[0].w;
                acc[i][0] += av[i].y * bv[1].x; acc[i][1] += av[i].y * bv[1].y;
                acc[i][2] += av[i].y * bv[1].z; acc[i][3] += av[i].y * bv[1].w;
                acc[i][0] += av[i].z * bv[2].x; acc[i][1] += av[i].z * bv[2].y;
                acc[i][2] += av[i].z * bv[2].z; acc[i][3] += av[i].z * bv[2].w;
                acc[i][0] += av[i].w * bv[3].x; acc[i][1] += av[i].w * bv[3].y;
                acc[i][2] += av[i].w * bv[3].z; acc[i][3] += av[i].w * bv[3].w;
            }
        }
        cfence();
        __builtin_amdgcn_sched_barrier(0);
        __builtin_amdgcn_s_barrier();        // reads done before overwrite
    }

    float* dst = part + s * (64 * M);
    #pragma unroll
    for (int i = 0; i < 4; ++i) {
        int u = ty * 4 + i;
        #pragma unroll
        for (int jj = 0; jj < 4; ++jj) {
            int j = o0 + tx * 4 + jj;
            if (j < M) dst[u * M + j] = acc[i][jj];
        }
    }
}

// ---------------------------------------------------------------------------
// k_red2: P2 = relu(b2 + sum_s part[s])   [64x500], 50 slices (verified r3)
// ---------------------------------------------------------------------------
__global__ __launch_bounds__(256) void k_red2(
    const float* __restrict__ part, const float* __restrict__ b2,
    float* __restrict__ P2)
{
    int i4 = blockIdx.x * 256 + threadIdx.x;
    if (i4 >= (64 * 500) / 4) return;
    int o = (i4 * 4) % 500;
    float4 acc = ldf4(b2 + o);
    #pragma unroll 10
    for (int s = 0; s < 50; ++s) {
        float4 v = ldf4(part + s * 32000 + i4 * 4);
        acc.x += v.x; acc.y += v.y; acc.z += v.z; acc.w += v.w;
    }
    acc.x = fmaxf(acc.x, 0.f); acc.y = fmaxf(acc.y, 0.f);
    acc.z = fmaxf(acc.z, 0.f); acc.w = fmaxf(acc.w, 0.f);
    *(float4*)(P2 + i4 * 4) = acc;
}

// ---------------------------------------------------------------------------
// k_red3: pre3 = b3 + sum_s part[s]   [64x100], 50 slices (verified r3)
// ---------------------------------------------------------------------------
__global__ __launch_bounds__(256) void k_red3(
    const float* __restrict__ part, const float* __restrict__ b3,
    float* __restrict__ pre3)
{
    int i4 = blockIdx.x * 256 + threadIdx.x;
    if (i4 >= (64 * 100) / 4) return;
    int o = (i4 * 4) % 100;
    float4 acc = ldf4(b3 + o);
    #pragma unroll 10
    for (int s = 0; s < 50; ++s) {
        float4 v = ldf4(part + s * 6400 + i4 * 4);
        acc.x += v.x; acc.y += v.y; acc.z += v.z; acc.w += v.w;
    }
    *(float4*)(pre3 + i4 * 4) = acc;
}

// ---------------------------------------------------------------------------
// k_head1: g[gi] = segsum relu(pre3); f1 = relu(c1 + g@W1)   (verified r3)
// ---------------------------------------------------------------------------
__global__ __launch_bounds__(256) void k_head1(
    const float* __restrict__ pre3, const int* __restrict__ batch,
    const float* __restrict__ W1, const float* __restrict__ c1,
    float* __restrict__ f1)
{
    const int gi = blockIdx.x >> 4;
    const int jt = blockIdx.x & 15;
    const int o0 = jt * 64;
    const int tid = threadIdx.x;
    __shared__ int   bsh[NN];
    __shared__ float gs[H3];
    __shared__ float red[4 * 64];

    if (tid < NN) bsh[tid] = batch[tid];
    __syncthreads();
    for (int d = tid; d < H3; d += 256) {
        float acc = 0.f;
        #pragma unroll
        for (int v = 0; v < NN; ++v) {
            float h = pre3[v * H3 + d];
            h = h > 0.f ? h : 0.f;
            acc += (bsh[v] == gi) ? h : 0.f;
        }
        gs[d] = acc;
    }
    __syncthreads();
    const int jj = tid & 63, kq = tid >> 6;
    const int oc = min(o0 + jj, FF1 - 1);
    float p = 0.f;
    #pragma unroll
    for (int k = kq * 25; k < kq * 25 + 25; ++k)
        p += gs[k] * W1[k * FF1 + oc];
    red[kq * 64 + jj] = p;
    __syncthreads();
    if (tid < 64) {
        int o = o0 + tid;
        if (o < FF1) {
            float v = c1[o] + red[tid] + red[64 + tid] + red[128 + tid] + red[192 + tid];
            f1[gi * FF1 + o] = v > 0.f ? v : 0.f;
        }
    }
}

// ---------------------------------------------------------------------------
// k_h2: ph[s][gi*100+o] = sum_{k in 40-chunk s} f1[gi][k]*W2[k][o] (ver. r8)
// ---------------------------------------------------------------------------
__global__ __launch_bounds__(256) void k_h2(
    const float* __restrict__ f1, const float* __restrict__ W2,
    float* __restrict__ ph)
{
    const int s = blockIdx.x;             // 0..24
    const int k0 = s * 40;
    const int tid = threadIdx.x;
    __shared__ float f1s[GG * 40];
    for (int i = tid; i < GG * 40; i += 256) {
        int gi = i / 40, kk = i - gi * 40;
        f1s[i] = f1[gi * FF1 + k0 + kk];
    }
    __syncthreads();
    for (int idx = tid; idx < GG * FF2; idx += 256) {
        int gi = idx / FF2, o = idx - gi * FF2;
        float acc = 0.f;
        #pragma unroll 8
        for (int kk = 0; kk < 40; ++kk)
            acc += f1s[gi * 40 + kk] * W2[(k0 + kk) * FF2 + o];
        ph[s * (GG * FF2) + idx] = acc;
    }
}

// ---------------------------------------------------------------------------
// k_head3: f2 = relu(c2 + sum_s ph[s]); f3 = relu(c3 + f2@W3);
//          out = f3@W4 + c4   (verified r8)
// ---------------------------------------------------------------------------
__global__ __launch_bounds__(256) void k_head3(
    const float* __restrict__ ph, const float* __restrict__ c2,
    const float* __restrict__ W3, const float* __restrict__ c3,
    const float* __restrict__ W4, const float* __restrict__ c4,
    float* __restrict__ out)
{
    const int tid = threadIdx.x;
    __shared__ float f2s[GG * FF2];
    __shared__ float f3s[GG * FF3];
    for (int idx = tid; idx < GG * FF2; idx += 256) {
        int o = idx % FF2;
        float acc = c2[o];
        #pragma unroll 5
        for (int s = 0; s < 25; ++s) acc += ph[s * (GG * FF2) + idx];
        f2s[idx] = acc > 0.f ? acc : 0.f;
    }
    __syncthreads();
    if (tid < GG * FF3) {
        int gi = tid / FF3, o = tid - gi * FF3;
        float acc = c3[o];
        #pragma unroll 4
        for (int k = 0; k < FF2; ++k)
            acc += f2s[gi * FF2 + k] * W3[k * FF3 + o];
        f3s[tid] = acc > 0.f ? acc : 0.f;
    }
    __syncthreads();
    if (tid < GG) {
        float acc = c4[0];
        #pragma unroll
        for (int k = 0; k < FF3; ++k) acc += f3s[tid * FF3 + k] * W4[k];
        out[tid] = acc;
    }
}

extern "C" void kernel_launch(void* const* d_in, const int* in_sizes, int n_in,
                              void* d_out, int out_size, void* d_ws, size_t ws_size,
                              hipStream_t stream) {
    const float* x          = (const float*)d_in[0];
    const int*   edge_index = (const int*)  d_in[1];
    const float* edge_attr  = (const float*)d_in[2];
    const int*   batch      = (const int*)  d_in[3];
    const float* We1 = (const float*)d_in[4];
    const float* be1 = (const float*)d_in[5];
    const float* root1 = (const float*)d_in[6];
    const float* b1  = (const float*)d_in[7];
    const float* We2 = (const float*)d_in[8];
    const float* be2 = (const float*)d_in[9];
    const float* root2 = (const float*)d_in[10];
    const float* b2  = (const float*)d_in[11];
    const float* We3 = (const float*)d_in[12];
    const float* be3 = (const float*)d_in[13];
    const float* root3 = (const float*)d_in[14];
    const float* b3  = (const float*)d_in[15];
    const float* W1 = (const float*)d_in[16];
    const float* c1 = (const float*)d_in[17];
    const float* W2 = (const float*)d_in[18];
    const float* c2 = (const float*)d_in[19];
    const float* W3 = (const float*)d_in[20];
    const float* c3 = (const float*)d_in[21];
    const float* W4 = (const float*)d_in[22];
    const float* c4 = (const float*)d_in[23];
    float* ws  = (float*)d_ws;
    float* out = (float*)d_out;

    // 1. P1 = relu(b1 + Y @ Wall1)      (Y built per-block in LDS)
    k_p1<<<32, 256, 0, stream>>>(x, edge_index, edge_attr,
                                 We1, be1, root1, b1, ws + OFF_P1);
    // 2. Q2f = A_d @ P1                 (6d x 16kt)
    k_qp<2000, 12000, 16><<<96, 256, 0, stream>>>(edge_index, edge_attr,
                                                  ws + OFF_P1, ws + OFF_Q);
    // 3. part2[50][64x500] = Q2f @ Wstack2
    k_split<500, 50, 12, 8000, 10000><<<400, 256, 0, stream>>>(
        ws + OFF_Q, We2, be2, root2, ws + OFF_PART);
    // 4. P2 = relu(b2 + sum part2)      (single cheap pass, no redundancy)
    k_red2<<<32, 256, 0, stream>>>(ws + OFF_PART, b2, ws + OFF_P2);
    // 5. Q3f = A_d @ P2                 (6d x 4kt)
    k_qp<500, 3000, 4><<<24, 256, 0, stream>>>(edge_index, edge_attr,
                                               ws + OFF_P2, ws + OFF_Q);
    // 6. part3[50][64x100] = Q3f @ Wstack3
    k_split<100, 50, 3, 2000, 2500><<<100, 256, 0, stream>>>(
        ws + OFF_Q, We3, be3, root3, ws + OFF_PART);
    // 7. pre3 = b3 + sum part3          (single cheap pass)
    k_red3<<<7, 256, 0, stream>>>(ws + OFF_PART, b3, ws + OFF_PRE3);
    // 8. f1 = relu(c1 + segsum(relu(pre3)) @ W1)
    k_head1<<<64, 256, 0, stream>>>(ws + OFF_PRE3, batch, W1, c1,
                                    ws + OFF_F1);
    // 9. ph = K-sliced f1 @ W2 partials
    k_h2<<<25, 256, 0, stream>>>(ws + OFF_F1, W2, ws + OFF_PH);
    // 10. out = head3(relu(c2 + sum ph))
    k_head3<<<1, 256, 0, stream>>>(ws + OFF_PH, c2, W3, c3, W4, c4, out);
}

// Round 11
// 204.206 us; speedup vs baseline: 2.3054x; 1.0430x over previous
//
#include <hip/hip_runtime.h>

// Problem dims
#define NN 64
#define EE 128
#define GG 4
#define D0 9
#define H1 2000
#define H2 500
#define H3 100
#define FF1 1000
#define FF2 100
#define FF3 50

// Workspace layout (floats)
#define OFF_P1   28032     // 64*2000           relu(pre1)
#define OFF_Q    156032    // 64*12000          Q2f (Q3f overlays)
#define OFF_PART 924032    // 100*64*500 = 3.2M partials (layer3 overlays)
#define OFF_P2   4124032   // 64*500            relu(pre2)
#define OFF_PRE3 4156032   // 64*100            pre3 (raw)
#define OFF_F1   4162432   // 4*1000
#define OFF_PH   4166448   // 25*400            head2 K-slice partials
// total ~16.7 MB

// ---------------------------------------------------------------------------
// async global->LDS 16B copy. LDS dest is wave-uniform base + lane*16;
// global source address is per-lane.
// ---------------------------------------------------------------------------
__device__ __forceinline__ void gl2lds16(const float* g, float* l) {
    __builtin_amdgcn_global_load_lds(
        (const __attribute__((address_space(1))) unsigned int*)g,
        (__attribute__((address_space(3))) unsigned int*)l,
        16, 0, 0);
}

__device__ __forceinline__ float4 ldf4(const float* p) {
    return *(const float4*)p;
}

// counted vmcnt wait (wave-uniform n). "memory" clobber = compiler fence.
__device__ __forceinline__ void waitcnt_vm_n(int n) {
    switch (n) {
    case 0: asm volatile("s_waitcnt vmcnt(0)" ::: "memory"); break;
    case 2: asm volatile("s_waitcnt vmcnt(2)" ::: "memory"); break;
    case 4: asm volatile("s_waitcnt vmcnt(4)" ::: "memory"); break;
    default: asm volatile("s_waitcnt vmcnt(6)" ::: "memory"); break;
    }
}
__device__ __forceinline__ void cfence() { asm volatile("" ::: "memory"); }

// ---------------------------------------------------------------------------
// per-block A_d row-slice build in LDS: rows v0..v0+NR-1 of A_d[v][u].
// d<4: edge_attr scatter; d==4: edge count; d==5: identity.
// Caller syncs after.
// ---------------------------------------------------------------------------
template<int NR>
__device__ __forceinline__ void build_Ad_rows(float* Al, int d, int v0,
    const int* __restrict__ ei, const float* __restrict__ ea, int tid)
{
    for (int i = tid; i < NR * 64; i += 256) Al[i] = 0.f;
    __syncthreads();
    if (d == 5) {
        if (tid >= v0 && tid < v0 + NR && tid < NN)
            Al[(tid - v0) * 64 + tid] = 1.0f;
    } else if (tid < EE) {
        int s = ei[tid], t = ei[EE + tid];
        if (t >= v0 && t < v0 + NR) {
            float v = (d < 4) ? ea[tid * 4 + d] : 1.0f;
            atomicAdd(&Al[(t - v0) * 64 + s], v);
        }
    }
}

// ---------------------------------------------------------------------------
// q compute core: Qf[v0+rg*NRG+i, d*Kd+k] = sum_u Al[(local v)][u]*Pl[u][k]
// thread = (col-quad kq 0..31, row-group rg 0..7 of NRG rows).
// ---------------------------------------------------------------------------
template<int Kd, int KTOT, int NRG>
__device__ __forceinline__ void q_compute_store(
    const float* Al, const float* Pl, float* __restrict__ Qf,
    int d, int k0, int v0, int tid)
{
    const int kq = tid & 31, rg = tid >> 5;
    float acc[NRG][4] = {};
    #pragma unroll 4
    for (int u4 = 0; u4 < 16; ++u4) {
        float4 pv0 = ldf4(&Pl[(u4 * 4 + 0) * 128 + kq * 4]);
        float4 pv1 = ldf4(&Pl[(u4 * 4 + 1) * 128 + kq * 4]);
        float4 pv2 = ldf4(&Pl[(u4 * 4 + 2) * 128 + kq * 4]);
        float4 pv3 = ldf4(&Pl[(u4 * 4 + 3) * 128 + kq * 4]);
        #pragma unroll
        for (int i = 0; i < NRG; ++i) {
            float4 a = ldf4(&Al[(rg * NRG + i) * 64 + u4 * 4]);
            acc[i][0] += a.x * pv0.x + a.y * pv1.x + a.z * pv2.x + a.w * pv3.x;
            acc[i][1] += a.x * pv0.y + a.y * pv1.y + a.z * pv2.y + a.w * pv3.y;
            acc[i][2] += a.x * pv0.z + a.y * pv1.z + a.z * pv2.z + a.w * pv3.z;
            acc[i][3] += a.x * pv0.w + a.y * pv1.w + a.z * pv2.w + a.w * pv3.w;
        }
    }
    const int k = k0 + kq * 4;
    if (k < Kd) {
        #pragma unroll
        for (int i = 0; i < NRG; ++i) {
            int r = v0 + rg * NRG + i;
            *(float4*)(Qf + r * KTOT + d * Kd + k) =
                make_float4(acc[i][0], acc[i][1], acc[i][2], acc[i][3]);
        }
    }
}

// ---------------------------------------------------------------------------
// K1: P1 = relu(b1 + Y @ Wall1). Y built per-block in LDS (verified r7-r10).
// ---------------------------------------------------------------------------
__global__ __launch_bounds__(256) void k_p1(
    const float* __restrict__ x, const int* __restrict__ edge_index,
    const float* __restrict__ edge_attr,
    const float* __restrict__ We1, const float* __restrict__ be1,
    const float* __restrict__ root1, const float* __restrict__ b1,
    float* __restrict__ P1)
{
    __shared__ float Ys[64 * 56];
    __shared__ __align__(16) float Bs[54 * 64];
    const int tid = threadIdx.x;
    const int tx = tid & 15, ty = tid >> 4;
    const int o0 = blockIdx.x * 64;
    const int w = min(64, H1 - o0);      // 32*64=2048 > 2000

    for (int i = tid; i < 64 * 56; i += 256) Ys[i] = 0.f;
    __syncthreads();
    if (tid < EE) {
        int s = edge_index[tid], t = edge_index[EE + tid];
        float ea[4];
        #pragma unroll
        for (int d = 0; d < 4; ++d) ea[d] = edge_attr[tid * 4 + d];
        #pragma unroll
        for (int i = 0; i < D0; ++i) {
            float xv = x[s * D0 + i];
            #pragma unroll
            for (int d = 0; d < 4; ++d)
                atomicAdd(&Ys[t * 56 + d * 9 + i], ea[d] * xv);
            atomicAdd(&Ys[t * 56 + 36 + i], xv);
        }
    }
    if (tid < NN) {
        #pragma unroll
        for (int i = 0; i < D0; ++i) Ys[tid * 56 + 45 + i] = x[tid * D0 + i];
    }
    for (int i = tid; i < 54 * 64; i += 256) {
        int r = i >> 6, c = i & 63;
        int d = r / 9, ii = r - d * 9;
        const float* rowp = ((d < 4) ? (We1 + d * (D0 * H1))
                                     : ((d == 4) ? be1 : root1)) + ii * H1;
        Bs[r * 64 + c] = (c < w) ? rowp[o0 + c] : 0.f;
    }
    __syncthreads();

    float acc[4][4] = {};
    #pragma unroll 6
    for (int r = 0; r < 54; ++r) {
        float a0 = Ys[(ty * 4 + 0) * 56 + r];
        float a1 = Ys[(ty * 4 + 1) * 56 + r];
        float a2 = Ys[(ty * 4 + 2) * 56 + r];
        float a3 = Ys[(ty * 4 + 3) * 56 + r];
        const float4 bv = *(const float4*)&Bs[r * 64 + tx * 4];
        acc[0][0] += a0 * bv.x; acc[0][1] += a0 * bv.y; acc[0][2] += a0 * bv.z; acc[0][3] += a0 * bv.w;
        acc[1][0] += a1 * bv.x; acc[1][1] += a1 * bv.y; acc[1][2] += a1 * bv.z; acc[1][3] += a1 * bv.w;
        acc[2][0] += a2 * bv.x; acc[2][1] += a2 * bv.y; acc[2][2] += a2 * bv.z; acc[2][3] += a2 * bv.w;
        acc[3][0] += a3 * bv.x; acc[3][1] += a3 * bv.y; acc[3][2] += a3 * bv.z; acc[3][3] += a3 * bv.w;
    }
    #pragma unroll
    for (int i = 0; i < 4; ++i) {
        int u = ty * 4 + i;
        #pragma unroll
        for (int jj = 0; jj < 4; ++jj) {
            int j = o0 + tx * 4 + jj;
            if (j < H1) {
                float v = b1[j] + acc[i][jj];
                P1[u * H1 + j] = v > 0.f ? v : 0.f;
            }
        }
    }
}

// ---------------------------------------------------------------------------
// k_qp: Qf row-slice = A_d(rows) @ P. RS-way row split for parallelism:
// block = (d, kt, rh); A-build stores only its NR=64/RS rows (less LDS).
// ---------------------------------------------------------------------------
template<int Kd, int KTOT, int NKT, int RS>
__global__ __launch_bounds__(256) void k_qp(
    const int* __restrict__ edge_index, const float* __restrict__ edge_attr,
    const float* __restrict__ P, float* __restrict__ Qf)
{
    constexpr int NR = 64 / RS;
    __shared__ __align__(16) float Al[NR * 64];
    __shared__ __align__(16) float Pl[64 * 128];
    const int tid = threadIdx.x;
    const int bx = blockIdx.x;
    const int d = bx / (NKT * RS);
    const int rem = bx % (NKT * RS);
    const int kt = rem / RS, rh = rem % RS;
    const int k0 = kt * 128;
    const int v0 = rh * NR;
    const int nf4 = (min(128, Kd - k0) + 3) >> 2;

    build_Ad_rows<NR>(Al, d, v0, edge_index, edge_attr, tid);
    for (int i4 = tid; i4 < 2048; i4 += 256) {
        int u = i4 >> 5, c4 = i4 & 31;
        float4 v = {0.f, 0.f, 0.f, 0.f};
        if (c4 < nf4) v = ldf4(P + u * Kd + k0 + c4 * 4);
        *(float4*)&Pl[u * 128 + c4 * 4] = v;
    }
    __syncthreads();
    q_compute_store<Kd, KTOT, NR / 8>(Al, Pl, Qf, d, k0, v0, tid);
}

// ---------------------------------------------------------------------------
// k_split: part[s][64][M] = Qf[64 x span] @ Wstk (col stripe o0..o0+63).
//   Counted-vmcnt double buffer (verified r3/r8/r10). Non-atomic slices.
// ---------------------------------------------------------------------------
template<int M, int S, int ITERS, int T1, int T2>
__global__ __launch_bounds__(256) void k_split(
    const float* __restrict__ Qf, const float* __restrict__ We,
    const float* __restrict__ be, const float* __restrict__ root,
    float* __restrict__ part)
{
    constexpr int KC = 20, BN = 64;
    constexpr int KTOT = S * ITERS * KC;
    const int b = blockIdx.x;
    const int s = b % S, ot = b / S;
    const int o0 = ot * BN;
    const int tid = threadIdx.x;
    const int tx = tid & 15, ty = tid >> 4;
    const int wv = tid >> 6, ln = tid & 63;
    const int kbase = s * (KC * ITERS);
    const int nw = (wv == 0) ? 4 : 2;   // per-wave VMEM issues per stage()

    __shared__ __align__(16) float As[2][64 * KC];   // [row][k]
    __shared__ __align__(16) float Bs[2][KC * BN];   // [k][col]

    auto stage = [&](int bf, int kb) {
        for (int c = wv; c < 5; c += 4) {            // A: 1280 fl = 5 chunks
            int f = c * 256 + ln * 4;
            int r = f / KC, kkk = f - r * KC;
            gl2lds16(Qf + r * KTOT + kb + kkk, &As[bf][c * 256]);
        }
        for (int c = wv; c < 5; c += 4) {            // B: 1280 fl = 5 chunks
            int f = c * 256 + ln * 4;
            int krow = f >> 6, col = f & 63;
            int kg = kb + krow;
            const float* bp = (kg < T1) ? (We + (long long)kg * M)
                            : (kg < T2) ? (be + (long long)(kg - T1) * M)
                                        : (root + (long long)(kg - T2) * M);
            int cc = min(o0 + col, M - 4);           // clamp keeps 16B align
            gl2lds16(bp + cc, &Bs[bf][c * 256]);
        }
    };

    float acc[4][4] = {};
    stage(0, kbase);
    for (int it = 0; it < ITERS; ++it) {
        int npend = 0;
        if (it + 1 < ITERS) { stage((it + 1) & 1, kbase + (it + 1) * KC); npend = nw; }
        waitcnt_vm_n(npend);                 // own current-buf loads done
        __builtin_amdgcn_s_barrier();        // all waves' writes visible
        __builtin_amdgcn_sched_barrier(0);

        const float* Ab = As[it & 1];
        const float* Bb = Bs[it & 1];
        #pragma unroll
        for (int k4 = 0; k4 < 5; ++k4) {
            float4 av[4], bv[4];
            #pragma unroll
            for (int i = 0; i < 4; ++i)
                av[i] = ldf4(&Ab[(ty * 4 + i) * KC + k4 * 4]);
            #pragma unroll
            for (int q = 0; q < 4; ++q)
                bv[q] = ldf4(&Bb[(k4 * 4 + q) * BN + tx * 4]);
            #pragma unroll
            for (int i = 0; i < 4; ++i) {
                acc[i][0] += av[i].x * bv[0].x; acc[i][1] += av[i].x * bv[0].y;
                acc[i][2] += av[i].x * bv[0].z; acc[i][3] += av[i].x * bv[0].w;
                acc[i][0] += av[i].y * bv[1].x; acc[i][1] += av[i].y * bv[1].y;
                acc[i][2] += av[i].y * bv[1].z; acc[i][3] += av[i].y * bv[1].w;
                acc[i][0] += av[i].z * bv[2].x; acc[i][1] += av[i].z * bv[2].y;
                acc[i][2] += av[i].z * bv[2].z; acc[i][3] += av[i].z * bv[2].w;
                acc[i][0] += av[i].w * bv[3].x; acc[i][1] += av[i].w * bv[3].y;
                acc[i][2] += av[i].w * bv[3].z; acc[i][3] += av[i].w * bv[3].w;
            }
        }
        cfence();
        __builtin_amdgcn_sched_barrier(0);
        __builtin_amdgcn_s_barrier();        // reads done before overwrite
    }

    float* dst = part + s * (64 * M);
    #pragma unroll
    for (int i = 0; i < 4; ++i) {
        int u = ty * 4 + i;
        #pragma unroll
        for (int jj = 0; jj < 4; ++jj) {
            int j = o0 + tx * 4 + jj;
            if (j < M) dst[u * M + j] = acc[i][jj];
        }
    }
}

// ---------------------------------------------------------------------------
// k_red2: P2 = relu(b2 + sum_s part[s])   [64x500], NS slices
// ---------------------------------------------------------------------------
template<int NS>
__global__ __launch_bounds__(256) void k_red2(
    const float* __restrict__ part, const float* __restrict__ b2,
    float* __restrict__ P2)
{
    int i4 = blockIdx.x * 256 + threadIdx.x;
    if (i4 >= (64 * 500) / 4) return;
    int o = (i4 * 4) % 500;
    float4 acc = ldf4(b2 + o);
    #pragma unroll 10
    for (int s = 0; s < NS; ++s) {
        float4 v = ldf4(part + s * 32000 + i4 * 4);
        acc.x += v.x; acc.y += v.y; acc.z += v.z; acc.w += v.w;
    }
    acc.x = fmaxf(acc.x, 0.f); acc.y = fmaxf(acc.y, 0.f);
    acc.z = fmaxf(acc.z, 0.f); acc.w = fmaxf(acc.w, 0.f);
    *(float4*)(P2 + i4 * 4) = acc;
}

// ---------------------------------------------------------------------------
// k_red3: pre3 = b3 + sum_s part[s]   [64x100], NS slices (raw)
// ---------------------------------------------------------------------------
template<int NS>
__global__ __launch_bounds__(256) void k_red3(
    const float* __restrict__ part, const float* __restrict__ b3,
    float* __restrict__ pre3)
{
    int i4 = blockIdx.x * 256 + threadIdx.x;
    if (i4 >= (64 * 100) / 4) return;
    int o = (i4 * 4) % 100;
    float4 acc = ldf4(b3 + o);
    #pragma unroll 10
    for (int s = 0; s < NS; ++s) {
        float4 v = ldf4(part + s * 6400 + i4 * 4);
        acc.x += v.x; acc.y += v.y; acc.z += v.z; acc.w += v.w;
    }
    *(float4*)(pre3 + i4 * 4) = acc;
}

// ---------------------------------------------------------------------------
// k_head1: g[gi] = segsum relu(pre3); f1 = relu(c1 + g@W1)   (verified r3)
// ---------------------------------------------------------------------------
__global__ __launch_bounds__(256) void k_head1(
    const float* __restrict__ pre3, const int* __restrict__ batch,
    const float* __restrict__ W1, const float* __restrict__ c1,
    float* __restrict__ f1)
{
    const int gi = blockIdx.x >> 4;
    const int jt = blockIdx.x & 15;
    const int o0 = jt * 64;
    const int tid = threadIdx.x;
    __shared__ int   bsh[NN];
    __shared__ float gs[H3];
    __shared__ float red[4 * 64];

    if (tid < NN) bsh[tid] = batch[tid];
    __syncthreads();
    for (int d = tid; d < H3; d += 256) {
        float acc = 0.f;
        #pragma unroll
        for (int v = 0; v < NN; ++v) {
            float h = pre3[v * H3 + d];
            h = h > 0.f ? h : 0.f;
            acc += (bsh[v] == gi) ? h : 0.f;
        }
        gs[d] = acc;
    }
    __syncthreads();
    const int jj = tid & 63, kq = tid >> 6;
    const int oc = min(o0 + jj, FF1 - 1);
    float p = 0.f;
    #pragma unroll
    for (int k = kq * 25; k < kq * 25 + 25; ++k)
        p += gs[k] * W1[k * FF1 + oc];
    red[kq * 64 + jj] = p;
    __syncthreads();
    if (tid < 64) {
        int o = o0 + tid;
        if (o < FF1) {
            float v = c1[o] + red[tid] + red[64 + tid] + red[128 + tid] + red[192 + tid];
            f1[gi * FF1 + o] = v > 0.f ? v : 0.f;
        }
    }
}

// ---------------------------------------------------------------------------
// k_h2: ph[s][gi*100+o] = sum_{k in 40-chunk s} f1[gi][k]*W2[k][o] (ver. r8)
// ---------------------------------------------------------------------------
__global__ __launch_bounds__(256) void k_h2(
    const float* __restrict__ f1, const float* __restrict__ W2,
    float* __restrict__ ph)
{
    const int s = blockIdx.x;             // 0..24
    const int k0 = s * 40;
    const int tid = threadIdx.x;
    __shared__ float f1s[GG * 40];
    for (int i = tid; i < GG * 40; i += 256) {
        int gi = i / 40, kk = i - gi * 40;
        f1s[i] = f1[gi * FF1 + k0 + kk];
    }
    __syncthreads();
    for (int idx = tid; idx < GG * FF2; idx += 256) {
        int gi = idx / FF2, o = idx - gi * FF2;
        float acc = 0.f;
        #pragma unroll 8
        for (int kk = 0; kk < 40; ++kk)
            acc += f1s[gi * 40 + kk] * W2[(k0 + kk) * FF2 + o];
        ph[s * (GG * FF2) + idx] = acc;
    }
}

// ---------------------------------------------------------------------------
// k_head3: f2 = relu(c2 + sum_s ph[s]); f3 = relu(c3 + f2@W3);
//          out = f3@W4 + c4   (verified r8)
// ---------------------------------------------------------------------------
__global__ __launch_bounds__(256) void k_head3(
    const float* __restrict__ ph, const float* __restrict__ c2,
    const float* __restrict__ W3, const float* __restrict__ c3,
    const float* __restrict__ W4, const float* __restrict__ c4,
    float* __restrict__ out)
{
    const int tid = threadIdx.x;
    __shared__ float f2s[GG * FF2];
    __shared__ float f3s[GG * FF3];
    for (int idx = tid; idx < GG * FF2; idx += 256) {
        int o = idx % FF2;
        float acc = c2[o];
        #pragma unroll 5
        for (int s = 0; s < 25; ++s) acc += ph[s * (GG * FF2) + idx];
        f2s[idx] = acc > 0.f ? acc : 0.f;
    }
    __syncthreads();
    if (tid < GG * FF3) {
        int gi = tid / FF3, o = tid - gi * FF3;
        float acc = c3[o];
        #pragma unroll 4
        for (int k = 0; k < FF2; ++k)
            acc += f2s[gi * FF2 + k] * W3[k * FF3 + o];
        f3s[tid] = acc > 0.f ? acc : 0.f;
    }
    __syncthreads();
    if (tid < GG) {
        float acc = c4[0];
        #pragma unroll
        for (int k = 0; k < FF3; ++k) acc += f3s[tid * FF3 + k] * W4[k];
        out[tid] = acc;
    }
}

extern "C" void kernel_launch(void* const* d_in, const int* in_sizes, int n_in,
                              void* d_out, int out_size, void* d_ws, size_t ws_size,
                              hipStream_t stream) {
    const float* x          = (const float*)d_in[0];
    const int*   edge_index = (const int*)  d_in[1];
    const float* edge_attr  = (const float*)d_in[2];
    const int*   batch      = (const int*)  d_in[3];
    const float* We1 = (const float*)d_in[4];
    const float* be1 = (const float*)d_in[5];
    const float* root1 = (const float*)d_in[6];
    const float* b1  = (const float*)d_in[7];
    const float* We2 = (const float*)d_in[8];
    const float* be2 = (const float*)d_in[9];
    const float* root2 = (const float*)d_in[10];
    const float* b2  = (const float*)d_in[11];
    const float* We3 = (const float*)d_in[12];
    const float* be3 = (const float*)d_in[13];
    const float* root3 = (const float*)d_in[14];
    const float* b3  = (const float*)d_in[15];
    const float* W1 = (const float*)d_in[16];
    const float* c1 = (const float*)d_in[17];
    const float* W2 = (const float*)d_in[18];
    const float* c2 = (const float*)d_in[19];
    const float* W3 = (const float*)d_in[20];
    const float* c3 = (const float*)d_in[21];
    const float* W4 = (const float*)d_in[22];
    const float* c4 = (const float*)d_in[23];
    float* ws  = (float*)d_ws;
    float* out = (float*)d_out;

    // 1. P1 = relu(b1 + Y @ Wall1)      (Y built per-block in LDS)
    k_p1<<<32, 256, 0, stream>>>(x, edge_index, edge_attr,
                                 We1, be1, root1, b1, ws + OFF_P1);
    // 2. Q2f = A_d @ P1                 (6d x 16kt x 2 row-halves = 192)
    k_qp<2000, 12000, 16, 2><<<192, 256, 0, stream>>>(edge_index, edge_attr,
                                                      ws + OFF_P1, ws + OFF_Q);
    // 3. part2[100][64x500] = Q2f @ Wstack2   (8 ot x 100 s = 800 blocks)
    k_split<500, 100, 6, 8000, 10000><<<800, 256, 0, stream>>>(
        ws + OFF_Q, We2, be2, root2, ws + OFF_PART);
    // 4. P2 = relu(b2 + sum part2)      (100 slices, single cheap pass)
    k_red2<100><<<32, 256, 0, stream>>>(ws + OFF_PART, b2, ws + OFF_P2);
    // 5. Q3f = A_d @ P2                 (6d x 4kt x 2 row-halves = 48)
    k_qp<500, 3000, 4, 2><<<48, 256, 0, stream>>>(edge_index, edge_attr,
                                                  ws + OFF_P2, ws + OFF_Q);
    // 6. part3[150][64x100] = Q3f @ Wstack3   (2 ot x 150 s = 300 blocks)
    k_split<100, 150, 1, 2000, 2500><<<300, 256, 0, stream>>>(
        ws + OFF_Q, We3, be3, root3, ws + OFF_PART);
    // 7. pre3 = b3 + sum part3          (150 slices, single cheap pass)
    k_red3<150><<<7, 256, 0, stream>>>(ws + OFF_PART, b3, ws + OFF_PRE3);
    // 8. f1 = relu(c1 + segsum(relu(pre3)) @ W1)
    k_head1<<<64, 256, 0, stream>>>(ws + OFF_PRE3, batch, W1, c1,
                                    ws + OFF_F1);
    // 9. ph = K-sliced f1 @ W2 partials
    k_h2<<<25, 256, 0, stream>>>(ws + OFF_F1, W2, ws + OFF_PH);
    // 10. out = head3(relu(c2 + sum ph))
    k_head3<<<1, 256, 0, stream>>>(ws + OFF_PH, c2, W3, c3, W4, c4, out);
}